// Round 1
// baseline (96.787 us; speedup 1.0000x reference)
//
#include <hip/hip_runtime.h>
#include <hip/hip_bf16.h>
#include <stdint.h>

// SGPN similarity loss, fused: batched Gram (A·A^T, K=64) via bf16 MFMA +
// hinge epilogue + scalar mean reduction. B=4, C=64, N=4096, G=50.
//
// ws layout: [0, 2MB)   gA  : bf16 points, chunk-major tile images
//            [2MB, +64K) gR  : r[b*4096+n] = sum_c f~^2 (fp32, from rounded vals)
//            [.. , +64K) gK  : key (group id, or unique negative if target==-1)
//            [.. , +64K) gW  : float(target)

#define NT 32                      // tiles per batch (4096/128)
#define TRI 528                    // NT*(NT+1)/2
#define SCALE (1.0f/67108864.0f)   // 1/(B*N*N), exact power of two

typedef __attribute__((ext_vector_type(4))) float f32x4;
typedef __attribute__((ext_vector_type(8))) __bf16 bf16x8;

__device__ __forceinline__ void async_load16(const void* g, void* l) {
    __builtin_amdgcn_global_load_lds(
        (const __attribute__((address_space(1))) uint32_t*)g,
        (__attribute__((address_space(3))) uint32_t*)l,
        16, 0, 0);
}

// ---------------- prep: transpose+cast Fsim, compute r/key/w ----------------
// one thread per point; 64 coalesced channel loads; coalesced chunk-major writes
__global__ __launch_bounds__(256) void sgpn_prep(
    const float* __restrict__ Fsim, const int* __restrict__ target,
    unsigned short* __restrict__ gA, float* __restrict__ gR,
    float* __restrict__ gK, float* __restrict__ gW)
{
    int t = blockIdx.x * 256 + threadIdx.x;   // 0..16383
    int b = t >> 12;
    int n = t & 4095;
    const float* src = Fsim + (size_t)b * 64 * 4096 + n;
    int tile = n >> 7, row = n & 127;
    // tile image: 8 chunks x 128 rows x 8 bf16 (=16B); ushort units
    unsigned short* dst = gA + (size_t)(b * NT + tile) * 8192 + row * 8;

    float racc = 0.f;
    #pragma unroll
    for (int c8 = 0; c8 < 8; ++c8) {
        unsigned us[8];
        #pragma unroll
        for (int j = 0; j < 8; ++j) {
            float f = src[(size_t)(c8 * 8 + j) * 4096];
            unsigned u = __float_as_uint(f);
            u += 0x7fffu + ((u >> 16) & 1u);      // RNE to bf16
            us[j] = u >> 16;
            float fb = __uint_as_float((us[j]) << 16);
            racc = fmaf(fb, fb, racc);
        }
        uint4 pk;
        pk.x = us[0] | (us[1] << 16);
        pk.y = us[2] | (us[3] << 16);
        pk.z = us[4] | (us[5] << 16);
        pk.w = us[6] | (us[7] << 16);
        *(uint4*)(dst + c8 * 1024) = pk;
    }
    gR[t] = racc;
    int tg = target[t];
    gK[t] = (tg >= 0) ? (float)tg : -(float)(n + 2);  // unique key => matches only itself
    gW[t] = (float)tg;
}

// ---------------- main: triangular 128x128 tiles, MFMA + epilogue ----------------
__global__ __launch_bounds__(256) void sgpn_main(
    const unsigned short* __restrict__ gA,
    const float* __restrict__ gR, const float* __restrict__ gK,
    const float* __restrict__ gW, float* __restrict__ out)
{
    __shared__ __align__(16) unsigned short lA[8192];   // 16 KB, chunk-major
    __shared__ __align__(16) unsigned short lB[8192];
    __shared__ __align__(16) float sRr[128], sKr[128], sWr[128];
    __shared__ __align__(16) float sRc[128], sKc[128], sWc[128];
    __shared__ float sRed[4];

    int bid = blockIdx.x;
    int b = bid / TRI;
    int t = bid - b * TRI;
    // decode t -> (ti <= tj), j-major: t = tj*(tj+1)/2 + ti
    int tj = (int)((sqrtf(8.0f * (float)t + 1.0f) - 1.0f) * 0.5f);
    while ((tj + 1) * (tj + 2) / 2 <= t) ++tj;
    while (tj * (tj + 1) / 2 > t) --tj;
    int ti = t - tj * (tj + 1) / 2;

    int tid = threadIdx.x;

    // stage both tile images (16 KB each) via global_load_lds width-16
    const unsigned short* tileA = gA + (size_t)(b * NT + ti) * 8192;
    const unsigned short* tileB = gA + (size_t)(b * NT + tj) * 8192;
    #pragma unroll
    for (int it = 0; it < 4; ++it) {
        int e = it * 256 + tid;               // 0..1023 : 16B chunk index
        async_load16(tileA + e * 8, lA + e * 8);
        async_load16(tileB + e * 8, lB + e * 8);
    }
    {
        int half = tid >> 7;
        int p0 = tid & 127;
        int gp = b * 4096 + (half ? tj : ti) * 128 + p0;
        float rv = gR[gp], kv = gK[gp], wv = gW[gp];
        if (half == 0) { sRr[p0] = rv; sKr[p0] = kv; sWr[p0] = wv; }
        else           { sRc[p0] = rv; sKc[p0] = kv; sWc[p0] = wv; }
    }
    __syncthreads();   // compiler drains vmcnt (incl. global_load_lds) before barrier

    int lane = tid & 63;
    int wave = tid >> 6;
    int wr = wave >> 1, wc = wave & 1;    // 2x2 waves over the 128x128 tile
    int quad = lane >> 4, lcol = lane & 15;

    f32x4 acc[4][4];
    #pragma unroll
    for (int i = 0; i < 4; ++i)
        #pragma unroll
        for (int j = 0; j < 4; ++j)
            acc[i][j] = (f32x4)0.f;

    #pragma unroll
    for (int kb = 0; kb < 2; ++kb) {
        int chunk = kb * 4 + quad;            // k = chunk*8 + j
        bf16x8 fa[4], fb[4];
        #pragma unroll
        for (int i = 0; i < 4; ++i)
            fa[i] = *(const bf16x8*)&lA[chunk * 1024 + (wr * 64 + i * 16 + lcol) * 8];
        #pragma unroll
        for (int j = 0; j < 4; ++j)
            fb[j] = *(const bf16x8*)&lB[chunk * 1024 + (wc * 64 + j * 16 + lcol) * 8];
        #pragma unroll
        for (int i = 0; i < 4; ++i)
            #pragma unroll
            for (int j = 0; j < 4; ++j)
                acc[i][j] = __builtin_amdgcn_mfma_f32_16x16x32_bf16(fa[i], fb[j], acc[i][j], 0, 0, 0);
    }

    // epilogue: C/D layout col = lane&15, row = quad*4 + reg (m89-verified)
    float rcv[4], kcv[4], wcv[4];
    #pragma unroll
    for (int j = 0; j < 4; ++j) {
        int cl = wc * 64 + j * 16 + lcol;
        rcv[j] = sRc[cl]; kcv[j] = sKc[cl]; wcv[j] = sWc[cl];
    }

    float sum = 0.f;
    #pragma unroll
    for (int i = 0; i < 4; ++i) {
        int rb = wr * 64 + i * 16 + quad * 4;           // 4-aligned
        f32x4 rr4 = *(const f32x4*)&sRr[rb];
        f32x4 kr4 = *(const f32x4*)&sKr[rb];
        f32x4 wr4 = *(const f32x4*)&sWr[rb];
        #pragma unroll
        for (int r = 0; r < 4; ++r) {
            float rrow = rr4[r], krow = kr4[r], wrow = wr4[r];
            float psum = 0.f;
            #pragma unroll
            for (int j = 0; j < 4; ++j) {
                float g  = acc[i][j][r];
                float d0 = fmaf(-2.f, g, rrow + rcv[j]);
                float D  = fmaxf(d0, 0.f);
                float h  = fmaxf(fmaf(D, -2.f, 1.6f), 0.f);   // 2*max(0.8 - D, 0)
                float v  = (krow == kcv[j]) ? D : h;          // same-group/diag via key
                psum = fmaf(v, wcv[j], psum);
            }
            sum = fmaf(psum, wrow, sum);
        }
    }

    // reduce: wave shuffle -> LDS -> one atomic per block
    #pragma unroll
    for (int off = 32; off > 0; off >>= 1)
        sum += __shfl_down(sum, off, 64);
    if (lane == 0) sRed[wave] = sum;
    __syncthreads();
    if (tid == 0) {
        float tot = (sRed[0] + sRed[1]) + (sRed[2] + sRed[3]);
        float mult = (ti == tj) ? 1.f : 2.f;   // off-diagonal tiles counted twice
        atomicAdd(out, tot * mult * SCALE);
    }
}

extern "C" void kernel_launch(void* const* d_in, const int* in_sizes, int n_in,
                              void* d_out, int out_size, void* d_ws, size_t ws_size,
                              hipStream_t stream) {
    // d_in: [0]=l0_points (unused), [1]=Fsim fp32 [4,64,4096], [2]=target int32 [4,4096]
    const float* Fsim  = (const float*)d_in[1];
    const int* target  = (const int*)d_in[2];
    float* out = (float*)d_out;

    char* ws = (char*)d_ws;
    unsigned short* gA = (unsigned short*)ws;                 // 2 MB
    float* gR = (float*)(ws + (2u << 20));                    // 64 KB
    float* gK = (float*)(ws + (2u << 20) + (64u << 10));      // 64 KB
    float* gW = (float*)(ws + (2u << 20) + (128u << 10));     // 64 KB

    hipMemsetAsync(d_out, 0, sizeof(float), stream);
    sgpn_prep<<<64, 256, 0, stream>>>(Fsim, target, gA, gR, gK, gW);
    sgpn_main<<<4 * TRI, 256, 0, stream>>>(gA, gR, gK, gW, out);
}

// Round 2
// 78.678 us; speedup vs baseline: 1.2302x; 1.2302x over previous
//
#include <hip/hip_runtime.h>
#include <hip/hip_bf16.h>
#include <stdint.h>

// SGPN similarity loss, fused: batched Gram (A·A^T, K=64) via bf16 MFMA +
// hinge epilogue + scalar mean reduction. B=4, C=64, N=4096, G=50.
//
// R2: (a) removed same-address atomicAdd (2112 blocks -> 1 word serializes
//     ~tens of ns each); blocks store partials, tiny 3rd kernel reduces.
//     (b) prep kernel: 256 blocks (was 64), fully-coalesced loads, LDS
//     reduction for r — was 0.25 waves/SIMD with 64 latency-exposed loads.
//
// ws layout: [0, 2MB)    gA : bf16 points, chunk-major tile images
//            [+2MB, 64K) gR : r[b*4096+n] = sum_c f~^2 (fp32, rounded vals)
//            [..,  +64K) gK : key (group id, or unique negative if -1)
//            [..,  +64K) gW : float(target)
//            [..,  +9K)  gP : per-block partials (2112 floats)

#define NT 32                      // tiles per batch (4096/128)
#define TRI 528                    // NT*(NT+1)/2
#define NBLK (4*TRI)               // 2112 main blocks
#define SCALE (1.0f/67108864.0f)   // 1/(B*N*N), exact power of two

typedef __attribute__((ext_vector_type(4))) float f32x4;
typedef __attribute__((ext_vector_type(8))) __bf16 bf16x8;

__device__ __forceinline__ void async_load16(const void* g, void* l) {
    __builtin_amdgcn_global_load_lds(
        (const __attribute__((address_space(1))) uint32_t*)g,
        (__attribute__((address_space(3))) uint32_t*)l,
        16, 0, 0);
}

// ---------------- prep: transpose+cast Fsim, compute r/key/w ----------------
// block = 64 points; wave w handles channels [w*16, w*16+16) for all 64 points.
// All global loads/stores fully coalesced (256B / 1KB per wave instr).
__global__ __launch_bounds__(256) void sgpn_prep(
    const float* __restrict__ Fsim, const int* __restrict__ target,
    unsigned short* __restrict__ gA, float* __restrict__ gR,
    float* __restrict__ gK, float* __restrict__ gW)
{
    __shared__ float sPart[4][64];

    int blk = blockIdx.x;              // 0..255
    int b = blk >> 6;                  // batch
    int n0 = (blk & 63) * 64;          // first point of this block
    int lane = threadIdx.x & 63;
    int wave = threadIdx.x >> 6;       // channel group

    int n = n0 + lane;
    int gp = b * 4096 + n;
    const float* src = Fsim + (size_t)b * 64 * 4096 + n;
    int tile = n >> 7, row = n & 127;
    unsigned short* dst = gA + (size_t)(b * NT + tile) * 8192 + row * 8;

    float racc = 0.f;
    #pragma unroll
    for (int q = 0; q < 2; ++q) {               // two 8-channel chunks
        int chunk = wave * 2 + q;
        unsigned us[8];
        #pragma unroll
        for (int j = 0; j < 8; ++j) {
            float f = src[(size_t)(chunk * 8 + j) * 4096];
            unsigned u = __float_as_uint(f);
            u += 0x7fffu + ((u >> 16) & 1u);    // RNE to bf16
            us[j] = u >> 16;
            float fb = __uint_as_float(us[j] << 16);
            racc = fmaf(fb, fb, racc);
        }
        uint4 pk;
        pk.x = us[0] | (us[1] << 16);
        pk.y = us[2] | (us[3] << 16);
        pk.z = us[4] | (us[5] << 16);
        pk.w = us[6] | (us[7] << 16);
        *(uint4*)(dst + chunk * 1024) = pk;
    }
    sPart[wave][lane] = racc;
    __syncthreads();
    if (wave == 0) {
        gR[gp] = (sPart[0][lane] + sPart[1][lane]) +
                 (sPart[2][lane] + sPart[3][lane]);
        int tg = target[gp];
        gK[gp] = (tg >= 0) ? (float)tg : -(float)(n + 2);  // unique key
        gW[gp] = (float)tg;
    }
}

// ---------------- main: triangular 128x128 tiles, MFMA + epilogue ----------------
__global__ __launch_bounds__(256) void sgpn_main(
    const unsigned short* __restrict__ gA,
    const float* __restrict__ gR, const float* __restrict__ gK,
    const float* __restrict__ gW, float* __restrict__ gP)
{
    __shared__ __align__(16) unsigned short lA[8192];   // 16 KB, chunk-major
    __shared__ __align__(16) unsigned short lB[8192];
    __shared__ __align__(16) float sRr[128], sKr[128], sWr[128];
    __shared__ __align__(16) float sRc[128], sKc[128], sWc[128];
    __shared__ float sRed[4];

    int bid = blockIdx.x;
    int b = bid / TRI;
    int t = bid - b * TRI;
    // decode t -> (ti <= tj), j-major: t = tj*(tj+1)/2 + ti
    int tj = (int)((sqrtf(8.0f * (float)t + 1.0f) - 1.0f) * 0.5f);
    while ((tj + 1) * (tj + 2) / 2 <= t) ++tj;
    while (tj * (tj + 1) / 2 > t) --tj;
    int ti = t - tj * (tj + 1) / 2;

    int tid = threadIdx.x;

    const unsigned short* tileA = gA + (size_t)(b * NT + ti) * 8192;
    const unsigned short* tileB = gA + (size_t)(b * NT + tj) * 8192;
    #pragma unroll
    for (int it = 0; it < 4; ++it) {
        int e = it * 256 + tid;               // 16B chunk index
        async_load16(tileA + e * 8, lA + e * 8);
        async_load16(tileB + e * 8, lB + e * 8);
    }
    {
        int half = tid >> 7;
        int p0 = tid & 127;
        int gp = b * 4096 + (half ? tj : ti) * 128 + p0;
        float rv = gR[gp], kv = gK[gp], wv = gW[gp];
        if (half == 0) { sRr[p0] = rv; sKr[p0] = kv; sWr[p0] = wv; }
        else           { sRc[p0] = rv; sKc[p0] = kv; sWc[p0] = wv; }
    }
    __syncthreads();

    int lane = tid & 63;
    int wave = tid >> 6;
    int wr = wave >> 1, wc = wave & 1;
    int quad = lane >> 4, lcol = lane & 15;

    f32x4 acc[4][4];
    #pragma unroll
    for (int i = 0; i < 4; ++i)
        #pragma unroll
        for (int j = 0; j < 4; ++j)
            acc[i][j] = (f32x4)0.f;

    #pragma unroll
    for (int kb = 0; kb < 2; ++kb) {
        int chunk = kb * 4 + quad;
        bf16x8 fa[4], fb[4];
        #pragma unroll
        for (int i = 0; i < 4; ++i)
            fa[i] = *(const bf16x8*)&lA[chunk * 1024 + (wr * 64 + i * 16 + lcol) * 8];
        #pragma unroll
        for (int j = 0; j < 4; ++j)
            fb[j] = *(const bf16x8*)&lB[chunk * 1024 + (wc * 64 + j * 16 + lcol) * 8];
        #pragma unroll
        for (int i = 0; i < 4; ++i)
            #pragma unroll
            for (int j = 0; j < 4; ++j)
                acc[i][j] = __builtin_amdgcn_mfma_f32_16x16x32_bf16(fa[i], fb[j], acc[i][j], 0, 0, 0);
    }

    // epilogue: C/D layout col = lane&15, row = quad*4 + reg
    float rcv[4], kcv[4], wcv[4];
    #pragma unroll
    for (int j = 0; j < 4; ++j) {
        int cl = wc * 64 + j * 16 + lcol;
        rcv[j] = sRc[cl]; kcv[j] = sKc[cl]; wcv[j] = sWc[cl];
    }

    float sum = 0.f;
    #pragma unroll
    for (int i = 0; i < 4; ++i) {
        int rb = wr * 64 + i * 16 + quad * 4;
        f32x4 rr4 = *(const f32x4*)&sRr[rb];
        f32x4 kr4 = *(const f32x4*)&sKr[rb];
        f32x4 wr4 = *(const f32x4*)&sWr[rb];
        #pragma unroll
        for (int r = 0; r < 4; ++r) {
            float rrow = rr4[r], krow = kr4[r], wrow = wr4[r];
            float psum = 0.f;
            #pragma unroll
            for (int j = 0; j < 4; ++j) {
                float g  = acc[i][j][r];
                float d0 = fmaf(-2.f, g, rrow + rcv[j]);
                float D  = fmaxf(d0, 0.f);
                float h  = fmaxf(fmaf(D, -2.f, 1.6f), 0.f);   // 2*max(0.8-D,0)
                float v  = (krow == kcv[j]) ? D : h;
                psum = fmaf(v, wcv[j], psum);
            }
            sum = fmaf(psum, wrow, sum);
        }
    }

    #pragma unroll
    for (int off = 32; off > 0; off >>= 1)
        sum += __shfl_down(sum, off, 64);
    if (lane == 0) sRed[wave] = sum;
    __syncthreads();
    if (tid == 0) {
        float tot = (sRed[0] + sRed[1]) + (sRed[2] + sRed[3]);
        float mult = (ti == tj) ? 1.f : 2.f;
        gP[bid] = tot * mult;                 // plain store — no atomic
    }
}

// ---------------- final: reduce 2112 partials -> scalar mean ----------------
__global__ __launch_bounds__(256) void sgpn_reduce(
    const float* __restrict__ gP, float* __restrict__ out)
{
    __shared__ float sr[4];
    int tid = threadIdx.x;
    float s = 0.f;
    for (int i = tid; i < NBLK; i += 256) s += gP[i];
    #pragma unroll
    for (int off = 32; off > 0; off >>= 1)
        s += __shfl_down(s, off, 64);
    if ((tid & 63) == 0) sr[tid >> 6] = s;
    __syncthreads();
    if (tid == 0)
        out[0] = ((sr[0] + sr[1]) + (sr[2] + sr[3])) * SCALE;
}

extern "C" void kernel_launch(void* const* d_in, const int* in_sizes, int n_in,
                              void* d_out, int out_size, void* d_ws, size_t ws_size,
                              hipStream_t stream) {
    // d_in: [0]=l0_points (unused), [1]=Fsim fp32 [4,64,4096], [2]=target int32 [4,4096]
    const float* Fsim  = (const float*)d_in[1];
    const int* target  = (const int*)d_in[2];
    float* out = (float*)d_out;

    char* ws = (char*)d_ws;
    unsigned short* gA = (unsigned short*)ws;                 // 2 MB
    float* gR = (float*)(ws + (2u << 20));                    // 64 KB
    float* gK = (float*)(ws + (2u << 20) + (64u << 10));      // 64 KB
    float* gW = (float*)(ws + (2u << 20) + (128u << 10));     // 64 KB
    float* gP = (float*)(ws + (2u << 20) + (192u << 10));     // 8.25 KB

    sgpn_prep<<<256, 256, 0, stream>>>(Fsim, target, gA, gR, gK, gW);
    sgpn_main<<<NBLK, 256, 0, stream>>>(gA, gR, gK, gW, gP);
    sgpn_reduce<<<1, 256, 0, stream>>>(gP, out);
}

// Round 3
// 77.684 us; speedup vs baseline: 1.2459x; 1.0128x over previous
//
#include <hip/hip_runtime.h>
#include <hip/hip_bf16.h>
#include <stdint.h>

// SGPN similarity loss, fused: batched Gram (A·A^T, K=64) via bf16 MFMA +
// hinge epilogue + scalar mean reduction. B=4, C=64, N=4096, G=50.
//
// R3: persistent main kernel — 512 blocks (exactly 2/CU, 76 KB LDS), each
//     handles 4-5 tile-pairs with double-buffered global_load_lds staging:
//     pair q+1's staging issues before pair q's compute (one cold-stage
//     latency per BLOCK instead of per PAIR; no block re-dispatch).
//
// ws layout: [0, 2MB)    gA : bf16 points, chunk-major tile images
//            [+2MB, 64K) gR : r[n] = sum_c f~^2 (fp32, from rounded vals)
//            [..,  +64K) gK : key (group id, or unique negative if -1)
//            [..,  +64K) gW : float(target)
//            [..,  +2K)  gP : per-block partials (512 floats)

#define NT 32                      // tiles per batch (4096/128)
#define TRI 528                    // NT*(NT+1)/2
#define NPAIR (4*TRI)              // 2112 tile-pairs
#define NBLK 512                   // persistent main blocks (2/CU)
#define SCALE (1.0f/67108864.0f)   // 1/(B*N*N), exact power of two

typedef __attribute__((ext_vector_type(4))) float f32x4;
typedef __attribute__((ext_vector_type(8))) __bf16 bf16x8;

__device__ __forceinline__ void async_load16(const void* g, void* l) {
    __builtin_amdgcn_global_load_lds(
        (const __attribute__((address_space(1))) uint32_t*)g,
        (__attribute__((address_space(3))) uint32_t*)l,
        16, 0, 0);
}

// ---------------- prep: transpose+cast Fsim, compute r/key/w ----------------
// block = 64 points; wave w handles channels [w*16, w*16+16) for all 64 points.
__global__ __launch_bounds__(256) void sgpn_prep(
    const float* __restrict__ Fsim, const int* __restrict__ target,
    unsigned short* __restrict__ gA, float* __restrict__ gR,
    float* __restrict__ gK, float* __restrict__ gW)
{
    __shared__ float sPart[4][64];

    int blk = blockIdx.x;              // 0..255
    int b = blk >> 6;
    int n0 = (blk & 63) * 64;
    int lane = threadIdx.x & 63;
    int wave = threadIdx.x >> 6;

    int n = n0 + lane;
    int gp = b * 4096 + n;
    const float* src = Fsim + (size_t)b * 64 * 4096 + n;
    int tile = n >> 7, row = n & 127;
    unsigned short* dst = gA + (size_t)(b * NT + tile) * 8192 + row * 8;

    float racc = 0.f;
    #pragma unroll
    for (int q = 0; q < 2; ++q) {
        int chunk = wave * 2 + q;
        unsigned us[8];
        #pragma unroll
        for (int j = 0; j < 8; ++j) {
            float f = src[(size_t)(chunk * 8 + j) * 4096];
            unsigned u = __float_as_uint(f);
            u += 0x7fffu + ((u >> 16) & 1u);    // RNE to bf16
            us[j] = u >> 16;
            float fb = __uint_as_float(us[j] << 16);
            racc = fmaf(fb, fb, racc);
        }
        uint4 pk;
        pk.x = us[0] | (us[1] << 16);
        pk.y = us[2] | (us[3] << 16);
        pk.z = us[4] | (us[5] << 16);
        pk.w = us[6] | (us[7] << 16);
        *(uint4*)(dst + chunk * 1024) = pk;
    }
    sPart[wave][lane] = racc;
    __syncthreads();
    if (wave == 0) {
        gR[gp] = (sPart[0][lane] + sPart[1][lane]) +
                 (sPart[2][lane] + sPart[3][lane]);
        int tg = target[gp];
        gK[gp] = (tg >= 0) ? (float)tg : -(float)(n + 2);  // unique key
        gW[gp] = (float)tg;
    }
}

// ---------------- main: persistent, dbuf-staged 128x128 tile-pairs ----------------
__global__ __launch_bounds__(256, 2) void sgpn_main(
    const unsigned short* __restrict__ gA,
    const float* __restrict__ gR, const float* __restrict__ gK,
    const float* __restrict__ gW, float* __restrict__ gP)
{
    // [buf][A=0/B=1][8192] bf16 chunk-major tile images : 64 KB
    __shared__ __align__(16) unsigned short lT[2][2][8192];
    // [buf][row=0/col=1][R=0,K=1,W=2][128] : 12 KB
    __shared__ __align__(16) float sM[2][2][3][128];
    __shared__ float sRed[4];
    __shared__ float sMult[2];

    int tid = threadIdx.x;
    int lane = tid & 63;
    int wave = tid >> 6;
    int g = blockIdx.x;
    int np = (g < (NPAIR - 4 * NBLK)) ? 5 : 4;   // first 64 blocks take a 5th pair

    auto stage = [&](int P, int buf) {
        int b = P / TRI;
        int t = P - b * TRI;
        int tj = (int)((sqrtf(8.0f * (float)t + 1.0f) - 1.0f) * 0.5f);
        while ((tj + 1) * (tj + 2) / 2 <= t) ++tj;
        while (tj * (tj + 1) / 2 > t) --tj;
        int ti = t - tj * (tj + 1) / 2;

        const unsigned short* tA = gA + (size_t)(b * NT + ti) * 8192;
        const unsigned short* tB = gA + (size_t)(b * NT + tj) * 8192;
        #pragma unroll
        for (int it = 0; it < 4; ++it) {
            int e = it * 256 + tid;               // 16B chunk index
            async_load16(tA + e * 8, &lT[buf][0][e * 8]);
            async_load16(tB + e * 8, &lT[buf][1][e * 8]);
        }
        int half = tid >> 7, p0 = tid & 127;
        int gp = b * 4096 + (half ? tj : ti) * 128 + p0;
        sM[buf][half][0][p0] = gR[gp];
        sM[buf][half][1][p0] = gK[gp];
        sM[buf][half][2][p0] = gW[gp];
        if (tid == 0) sMult[buf] = (ti == tj) ? 1.f : 2.f;
    };

    int wr = wave >> 1, wc = wave & 1;
    int quad = lane >> 4, lcol = lane & 15;

    float total = 0.f;
    stage(g, 0);

    for (int q = 0; q < np; ++q) {
        __syncthreads();                       // drains staging of buf q&1
        int buf = q & 1;
        if (q + 1 < np) stage(g + (q + 1) * NBLK, buf ^ 1);  // async prefetch

        // ---- MFMA on buf ----
        f32x4 acc[4][4];
        #pragma unroll
        for (int i = 0; i < 4; ++i)
            #pragma unroll
            for (int j = 0; j < 4; ++j)
                acc[i][j] = (f32x4)0.f;

        #pragma unroll
        for (int kb = 0; kb < 2; ++kb) {
            int chunk = kb * 4 + quad;
            bf16x8 fa[4], fb[4];
            #pragma unroll
            for (int i = 0; i < 4; ++i)
                fa[i] = *(const bf16x8*)&lT[buf][0][chunk * 1024 + (wr * 64 + i * 16 + lcol) * 8];
            #pragma unroll
            for (int j = 0; j < 4; ++j)
                fb[j] = *(const bf16x8*)&lT[buf][1][chunk * 1024 + (wc * 64 + j * 16 + lcol) * 8];
            #pragma unroll
            for (int i = 0; i < 4; ++i)
                #pragma unroll
                for (int j = 0; j < 4; ++j)
                    acc[i][j] = __builtin_amdgcn_mfma_f32_16x16x32_bf16(fa[i], fb[j], acc[i][j], 0, 0, 0);
        }

        // ---- epilogue: C/D layout col = lane&15, row = quad*4 + reg ----
        float rcv[4], kcv[4], wcv[4];
        #pragma unroll
        for (int j = 0; j < 4; ++j) {
            int cl = wc * 64 + j * 16 + lcol;
            rcv[j] = sM[buf][1][0][cl];
            kcv[j] = sM[buf][1][1][cl];
            wcv[j] = sM[buf][1][2][cl];
        }

        float sum = 0.f;
        #pragma unroll
        for (int i = 0; i < 4; ++i) {
            int rb = wr * 64 + i * 16 + quad * 4;          // 4-aligned
            f32x4 rr4 = *(const f32x4*)&sM[buf][0][0][rb];
            f32x4 kr4 = *(const f32x4*)&sM[buf][0][1][rb];
            f32x4 wr4 = *(const f32x4*)&sM[buf][0][2][rb];
            #pragma unroll
            for (int r = 0; r < 4; ++r) {
                float rrow = rr4[r], krow = kr4[r], wrow = wr4[r];
                float psum = 0.f;
                #pragma unroll
                for (int j = 0; j < 4; ++j) {
                    float gacc = acc[i][j][r];
                    float d0 = fmaf(-2.f, gacc, rrow + rcv[j]);
                    float D  = fmaxf(d0, 0.f);
                    float h  = fmaxf(fmaf(D, -2.f, 1.6f), 0.f);   // 2*max(0.8-D,0)
                    float v  = (krow == kcv[j]) ? D : h;
                    psum = fmaf(v, wcv[j], psum);
                }
                sum = fmaf(psum, wrow, sum);
            }
        }
        total = fmaf(sum, sMult[buf], total);
    }

    // reduce: wave shuffle -> LDS -> one store per block
    #pragma unroll
    for (int off = 32; off > 0; off >>= 1)
        total += __shfl_down(total, off, 64);
    if (lane == 0) sRed[wave] = total;
    __syncthreads();
    if (tid == 0)
        gP[g] = (sRed[0] + sRed[1]) + (sRed[2] + sRed[3]);
}

// ---------------- final: reduce 512 partials -> scalar mean ----------------
__global__ __launch_bounds__(256) void sgpn_reduce(
    const float* __restrict__ gP, float* __restrict__ out)
{
    __shared__ float sr[4];
    int tid = threadIdx.x;
    float s = gP[tid] + gP[tid + 256];
    #pragma unroll
    for (int off = 32; off > 0; off >>= 1)
        s += __shfl_down(s, off, 64);
    if ((tid & 63) == 0) sr[tid >> 6] = s;
    __syncthreads();
    if (tid == 0)
        out[0] = ((sr[0] + sr[1]) + (sr[2] + sr[3])) * SCALE;
}

extern "C" void kernel_launch(void* const* d_in, const int* in_sizes, int n_in,
                              void* d_out, int out_size, void* d_ws, size_t ws_size,
                              hipStream_t stream) {
    // d_in: [0]=l0_points (unused), [1]=Fsim fp32 [4,64,4096], [2]=target int32 [4,4096]
    const float* Fsim  = (const float*)d_in[1];
    const int* target  = (const int*)d_in[2];
    float* out = (float*)d_out;

    char* ws = (char*)d_ws;
    unsigned short* gA = (unsigned short*)ws;                 // 2 MB
    float* gR = (float*)(ws + (2u << 20));                    // 64 KB
    float* gK = (float*)(ws + (2u << 20) + (64u << 10));      // 64 KB
    float* gW = (float*)(ws + (2u << 20) + (128u << 10));     // 64 KB
    float* gP = (float*)(ws + (2u << 20) + (192u << 10));     // 2 KB

    sgpn_prep<<<256, 256, 0, stream>>>(Fsim, target, gA, gR, gK, gW);
    sgpn_main<<<NBLK, 256, 0, stream>>>(gA, gR, gK, gW, gP);
    sgpn_reduce<<<1, 256, 0, stream>>>(gP, out);
}